// Round 1
// baseline (1221.282 us; speedup 1.0000x reference)
//
#include <hip/hip_runtime.h>

// Problem constants (Qwen3MoE attention prefill)
#define B_   2
#define S_   1024
#define HID_ 2048
#define H_   32
#define HK_  4
#define D_   128
#define NQKV ((H_ + 2 * HK_) * D_)   // 5120
#define TOK  (B_ * S_)               // 2048

typedef short bf16x8  __attribute__((ext_vector_type(8)));  // 8 bf16 (4 VGPRs)
typedef short short4v __attribute__((ext_vector_type(4)));
typedef float f32x4   __attribute__((ext_vector_type(4)));
typedef int   i32x4   __attribute__((ext_vector_type(4)));

__device__ inline short f2bf(float f) {
  unsigned u = __builtin_bit_cast(unsigned, f);
  u += 0x7fffu + ((u >> 16) & 1u);   // round-to-nearest-even
  return (short)(u >> 16);
}

// ---------------------------------------------------------------- cast fp32 -> bf16
__global__ __launch_bounds__(256) void cast_f32_bf16(const float* __restrict__ in,
                                                     short* __restrict__ out, int n4) {
  int i = blockIdx.x * 256 + threadIdx.x;
  if (i >= n4) return;
  f32x4 v = ((const f32x4*)in)[i];
  short4v o;
  o[0] = f2bf(v[0]); o[1] = f2bf(v[1]); o[2] = f2bf(v[2]); o[3] = f2bf(v[3]);
  ((short4v*)out)[i] = o;
}

// ---------------------------------------------------------------- transpose+cast: [K][N] f32 -> [N][K] bf16
__global__ __launch_bounds__(256) void transpose_cast(const float* __restrict__ in,
                                                      short* __restrict__ out,
                                                      int K, int N) {
  __shared__ float tile[32][33];
  int nb = blockIdx.x * 32, kb = blockIdx.y * 32;
  int c = threadIdx.x & 31, r0 = threadIdx.x >> 5;  // 8 rows per pass
#pragma unroll
  for (int i = 0; i < 4; i++) {
    int r = r0 + i * 8;
    tile[r][c] = in[(size_t)(kb + r) * N + nb + c];
  }
  __syncthreads();
#pragma unroll
  for (int i = 0; i < 4; i++) {
    int r = r0 + i * 8;
    out[(size_t)(nb + r) * K + kb + c] = f2bf(tile[c][r]);
  }
}

// ---------------------------------------------------------------- bf16 MFMA GEMM, C = A[M][K] * Bt[N][K]^T, fp32 out
__global__ __launch_bounds__(256) void gemm_bt(const short* __restrict__ A,
                                               const short* __restrict__ Bt,
                                               float* __restrict__ C,
                                               int M, int N, int K) {
  const int tid  = threadIdx.x;
  const int m0   = blockIdx.y * 64;
  const int n0   = blockIdx.x * 64;
  const int wave = tid >> 6, lane = tid & 63;
  const int quad = lane >> 4, l16 = lane & 15;
  const int wm   = (wave >> 1) * 32, wn = (wave & 1) * 32;

  // LDT = 72 shorts (=144 B = 36 banks): frag reads are 2-way (free), rows 16B-aligned
  __shared__ short As[64 * 72];
  __shared__ short Bs[64 * 72];

  const f32x4 z = {0.f, 0.f, 0.f, 0.f};
  f32x4 acc[2][2] = {{z, z}, {z, z}};

  for (int k0 = 0; k0 < K; k0 += 64) {
#pragma unroll
    for (int i = 0; i < 2; i++) {
      int idx = tid + i * 256;        // 0..511
      int r   = idx >> 3;             // 64 rows, 8 x 16B chunks each
      int c8  = idx & 7;
      *(i32x4*)&As[r * 72 + c8 * 8] = *(const i32x4*)&A [(size_t)(m0 + r) * K + k0 + c8 * 8];
      *(i32x4*)&Bs[r * 72 + c8 * 8] = *(const i32x4*)&Bt[(size_t)(n0 + r) * K + k0 + c8 * 8];
    }
    __syncthreads();
#pragma unroll
    for (int ks = 0; ks < 64; ks += 32) {
      bf16x8 a0 = *(const bf16x8*)&As[(wm +      l16) * 72 + ks + quad * 8];
      bf16x8 a1 = *(const bf16x8*)&As[(wm + 16 + l16) * 72 + ks + quad * 8];
      bf16x8 b0 = *(const bf16x8*)&Bs[(wn +      l16) * 72 + ks + quad * 8];
      bf16x8 b1 = *(const bf16x8*)&Bs[(wn + 16 + l16) * 72 + ks + quad * 8];
      acc[0][0] = __builtin_amdgcn_mfma_f32_16x16x32_bf16(a0, b0, acc[0][0], 0, 0, 0);
      acc[0][1] = __builtin_amdgcn_mfma_f32_16x16x32_bf16(a0, b1, acc[0][1], 0, 0, 0);
      acc[1][0] = __builtin_amdgcn_mfma_f32_16x16x32_bf16(a1, b0, acc[1][0], 0, 0, 0);
      acc[1][1] = __builtin_amdgcn_mfma_f32_16x16x32_bf16(a1, b1, acc[1][1], 0, 0, 0);
    }
    __syncthreads();
  }

  // C/D layout: col = lane&15, row = quad*4 + reg  [verified m89/m91]
#pragma unroll
  for (int i = 0; i < 2; i++)
#pragma unroll
    for (int j = 0; j < 2; j++) {
      int r0 = m0 + wm + 16 * i + quad * 4;
      int c  = n0 + wn + 16 * j + l16;
#pragma unroll
      for (int r = 0; r < 4; r++)
        C[(size_t)(r0 + r) * N + c] = acc[i][j][r];
    }
}

// ---------------------------------------------------------------- RMSNorm + RoPE in-place on q/k slices of qkv
__global__ __launch_bounds__(64) void rmsnorm_rope(float* __restrict__ qkv,
                                                   const float* __restrict__ cosT,
                                                   const float* __restrict__ sinT,
                                                   const float* __restrict__ qw,
                                                   const float* __restrict__ kw) {
  int t    = blockIdx.x;        // token 0..2047
  int hd   = blockIdx.y;        // 0..35: 0..31 q-heads, 32..35 k-heads
  int s    = t & (S_ - 1);
  int lane = threadIdx.x;       // 0..63; owns d=lane and d=lane+64
  float* base;
  const float* w;
  if (hd < H_) { base = qkv + (size_t)t * NQKV + hd * D_;                 w = qw; }
  else         { base = qkv + (size_t)t * NQKV + H_ * D_ + (hd - H_) * D_; w = kw; }
  float x1 = base[lane], x2 = base[lane + 64];
  float ss = x1 * x1 + x2 * x2;
#pragma unroll
  for (int off = 32; off > 0; off >>= 1) ss += __shfl_xor(ss, off, 64);
  float rn = rsqrtf(ss * (1.0f / 128.0f) + 1e-6f);
  float y1 = x1 * rn * w[lane], y2 = x2 * rn * w[lane + 64];
  float c1 = cosT[s * D_ + lane],      s1 = sinT[s * D_ + lane];
  float c2 = cosT[s * D_ + lane + 64], s2 = sinT[s * D_ + lane + 64];
  base[lane]      = y1 * c1 - y2 * s1;   // rotate_half: first half gets -x2*sin
  base[lane + 64] = y2 * c2 + y1 * s2;
}

// ---------------------------------------------------------------- fp32 flash attention (causal GQA), writes bf16 ctx
__global__ __launch_bounds__(256) void flash_attn(const float* __restrict__ qkv,
                                                  short* __restrict__ ctx) {
  const int qt = blockIdx.x;    // q tile (32 rows)
  const int h  = blockIdx.y;    // q head
  const int b  = blockIdx.z;
  const int kh = h >> 3;        // G = 8
  const int q0 = qt * 32;
  const int tid = threadIdx.x;

  __shared__ float Qs[32 * 132];
  __shared__ float Ks[32 * 132];
  __shared__ float Vs[32 * 132];
  __shared__ float Ps[32 * 33];
  __shared__ float alpha_s[32];
  __shared__ float l_s[32];

  const float scale = 0.08838834764831845f;  // 1/sqrt(128)

  // load Q tile, pre-scaled
#pragma unroll
  for (int i = 0; i < 4; i++) {
    int idx = tid + i * 256;
    int r = idx >> 5, c4 = idx & 31;
    f32x4 v = *(const f32x4*)&qkv[(size_t)(b * S_ + q0 + r) * NQKV + h * D_ + c4 * 4];
    *(f32x4*)&Qs[r * 132 + c4 * 4] = v * scale;
  }

  const f32x4 z = {0.f, 0.f, 0.f, 0.f};
  f32x4 O[4] = {z, z, z, z};
  float m_r = -INFINITY, l_r = 0.0f;

  const int r_s = tid >> 3;  // score/O row 0..31
  const int c8  = tid & 7;

  for (int kt = 0; kt <= qt; kt++) {
    int k0 = kt * 32;
    __syncthreads();  // protect Ks/Vs/Ps from previous iter readers (also covers Q-load)
#pragma unroll
    for (int i = 0; i < 4; i++) {
      int idx = tid + i * 256;
      int r = idx >> 5, c4 = idx & 31;
      size_t rowb = (size_t)(b * S_ + k0 + r) * NQKV;
      *(f32x4*)&Ks[r * 132 + c4 * 4] = *(const f32x4*)&qkv[rowb + H_ * D_ + kh * D_ + c4 * 4];
      *(f32x4*)&Vs[r * 132 + c4 * 4] = *(const f32x4*)&qkv[rowb + (H_ + HK_) * D_ + kh * D_ + c4 * 4];
    }
    __syncthreads();

    // scores: thread computes S[r_s][c8 + 8*ci], ci=0..3
    float sc0 = 0.f, sc1 = 0.f, sc2 = 0.f, sc3 = 0.f;
#pragma unroll 4
    for (int d4 = 0; d4 < 32; d4++) {
      f32x4 qv = ((const f32x4*)Qs)[r_s * 33 + d4];
      f32x4 k0v = ((const f32x4*)Ks)[(c8     ) * 33 + d4];
      f32x4 k1v = ((const f32x4*)Ks)[(c8 +  8) * 33 + d4];
      f32x4 k2v = ((const f32x4*)Ks)[(c8 + 16) * 33 + d4];
      f32x4 k3v = ((const f32x4*)Ks)[(c8 + 24) * 33 + d4];
      sc0 += qv[0]*k0v[0] + qv[1]*k0v[1] + qv[2]*k0v[2] + qv[3]*k0v[3];
      sc1 += qv[0]*k1v[0] + qv[1]*k1v[1] + qv[2]*k1v[2] + qv[3]*k1v[3];
      sc2 += qv[0]*k2v[0] + qv[1]*k2v[1] + qv[2]*k2v[2] + qv[3]*k2v[3];
      sc3 += qv[0]*k3v[0] + qv[1]*k3v[1] + qv[2]*k3v[2] + qv[3]*k3v[3];
    }
    float sc[4] = {sc0, sc1, sc2, sc3};
#pragma unroll
    for (int ci = 0; ci < 4; ci++) {
      int c = c8 + 8 * ci;
      Ps[r_s * 33 + c] = (k0 + c > q0 + r_s) ? -1e30f : sc[ci];
    }
    __syncthreads();

    // online softmax row pass (wave 0, one thread per row)
    if (tid < 32) {
      float mx = -1e30f;
#pragma unroll
      for (int c = 0; c < 32; c++) mx = fmaxf(mx, Ps[tid * 33 + c]);
      float m_new = fmaxf(m_r, mx);
      float a = __expf(m_r - m_new);
      float sum = 0.f;
#pragma unroll
      for (int c = 0; c < 32; c++) {
        float p = __expf(Ps[tid * 33 + c] - m_new);
        Ps[tid * 33 + c] = p;
        sum += p;
      }
      l_r = l_r * a + sum;
      m_r = m_new;
      alpha_s[tid] = a;
    }
    __syncthreads();

    // O update: thread owns row r_s, cols c8*4 + 32*ci + 0..3
    float a = alpha_s[r_s];
#pragma unroll
    for (int ci = 0; ci < 4; ci++) O[ci] *= a;
    for (int j = 0; j < 32; j++) {
      float p = Ps[r_s * 33 + j];
#pragma unroll
      for (int ci = 0; ci < 4; ci++) {
        f32x4 vv = ((const f32x4*)Vs)[j * 33 + c8 + 8 * ci];
        O[ci] += p * vv;
      }
    }
  }

  if (tid < 32) l_s[tid] = l_r;
  __syncthreads();
  float inv = 1.0f / l_s[r_s];
  size_t obase = (size_t)(b * S_ + q0 + r_s) * (H_ * D_) + h * D_;
#pragma unroll
  for (int ci = 0; ci < 4; ci++) {
    f32x4 o = O[ci];
    short4v o4;
    o4[0] = f2bf(o[0] * inv); o4[1] = f2bf(o[1] * inv);
    o4[2] = f2bf(o[2] * inv); o4[3] = f2bf(o[3] * inv);
    *(short4v*)&ctx[obase + c8 * 4 + 32 * ci] = o4;
  }
}

// ---------------------------------------------------------------- launch
extern "C" void kernel_launch(void* const* d_in, const int* in_sizes, int n_in,
                              void* d_out, int out_size, void* d_ws, size_t ws_size,
                              hipStream_t stream) {
  (void)in_sizes; (void)n_in; (void)out_size; (void)ws_size;
  const float* hidden = (const float*)d_in[0];
  const float* cosT   = (const float*)d_in[1];
  const float* sinT   = (const float*)d_in[2];
  const float* wqkv   = (const float*)d_in[3];
  const float* qnw    = (const float*)d_in[4];
  const float* knw    = (const float*)d_in[5];
  const float* wo     = (const float*)d_in[6];
  float* out = (float*)d_out;

  char* ws = (char*)d_ws;
  float* qkv = (float*)(ws);                                  // 2048*5120 f32  = 41,943,040 B
  short* hb  = (short*)(ws + 41943040);                       // 2048*2048 bf16 =  8,388,608 B
  short* wT  = (short*)(ws + 41943040 + 8388608);             // 5120*2048 bf16 = 20,971,520 B (reused for w_oT)
  short* ctx = (short*)(ws + 41943040 + 8388608 + 20971520);  // 2048*4096 bf16 = 16,777,216 B
  // total 88,080,384 B

  // 1. hidden -> bf16
  cast_f32_bf16<<<4096, 256, 0, stream>>>(hidden, hb, TOK * HID_ / 4);
  // 2. w_qkv [2048][5120] -> bf16 [5120][2048]
  transpose_cast<<<dim3(NQKV / 32, HID_ / 32), 256, 0, stream>>>(wqkv, wT, HID_, NQKV);
  // 3. qkv = hidden @ w_qkv   (M=2048, N=5120, K=2048)
  gemm_bt<<<dim3(NQKV / 64, TOK / 64), 256, 0, stream>>>(hb, wT, qkv, TOK, NQKV, HID_);
  // 4. RMSNorm + RoPE in-place on q,k
  rmsnorm_rope<<<dim3(TOK, H_ + HK_), 64, 0, stream>>>(qkv, cosT, sinT, qnw, knw);
  // 5. causal GQA flash attention -> ctx bf16 [2048][4096]
  flash_attn<<<dim3(S_ / 32, H_, B_), 256, 0, stream>>>(qkv, ctx);
  // 6. w_o [4096][2048] -> bf16 [2048][4096]  (reuse wT; after gemm1 is done in stream order)
  transpose_cast<<<dim3(HID_ / 32, (H_ * D_) / 32), 256, 0, stream>>>(wo, wT, H_ * D_, HID_);
  // 7. out = ctx @ w_o   (M=2048, N=2048, K=4096)
  gemm_bt<<<dim3(HID_ / 64, TOK / 64), 256, 0, stream>>>(ctx, wT, out, TOK, HID_, H_ * D_);
}

// Round 2
// 462.214 us; speedup vs baseline: 2.6422x; 2.6422x over previous
//
#include <hip/hip_runtime.h>

// Problem constants (Qwen3MoE attention prefill)
#define B_   2
#define S_   1024
#define HID_ 2048
#define H_   32
#define HK_  4
#define D_   128
#define NQKV ((H_ + 2 * HK_) * D_)   // 5120
#define TOK  (B_ * S_)               // 2048

typedef short bf16x8  __attribute__((ext_vector_type(8)));  // 8 bf16 (4 VGPRs)
typedef short short4v __attribute__((ext_vector_type(4)));
typedef float f32x4   __attribute__((ext_vector_type(4)));
typedef int   i32x4   __attribute__((ext_vector_type(4)));

__device__ inline short f2bf(float f) {
  unsigned u = __builtin_bit_cast(unsigned, f);
  u += 0x7fffu + ((u >> 16) & 1u);   // round-to-nearest-even
  return (short)(u >> 16);
}

// ---------------------------------------------------------------- cast fp32 -> bf16
__global__ __launch_bounds__(256) void cast_f32_bf16(const float* __restrict__ in,
                                                     short* __restrict__ out, int n4) {
  int i = blockIdx.x * 256 + threadIdx.x;
  if (i >= n4) return;
  f32x4 v = ((const f32x4*)in)[i];
  short4v o;
  o[0] = f2bf(v[0]); o[1] = f2bf(v[1]); o[2] = f2bf(v[2]); o[3] = f2bf(v[3]);
  ((short4v*)out)[i] = o;
}

// ---------------------------------------------------------------- transpose+cast: [K][N] f32 -> [N][K] bf16
__global__ __launch_bounds__(256) void transpose_cast(const float* __restrict__ in,
                                                      short* __restrict__ out,
                                                      int K, int N) {
  __shared__ float tile[32][33];
  int nb = blockIdx.x * 32, kb = blockIdx.y * 32;
  int c = threadIdx.x & 31, r0 = threadIdx.x >> 5;  // 8 rows per pass
#pragma unroll
  for (int i = 0; i < 4; i++) {
    int r = r0 + i * 8;
    tile[r][c] = in[(size_t)(kb + r) * N + nb + c];
  }
  __syncthreads();
#pragma unroll
  for (int i = 0; i < 4; i++) {
    int r = r0 + i * 8;
    out[(size_t)(nb + r) * K + kb + c] = f2bf(tile[c][r]);
  }
}

// ---------------------------------------------------------------- bf16 MFMA GEMM, C = A[M][K] * Bt[N][K]^T, fp32 out
__global__ __launch_bounds__(256) void gemm_bt(const short* __restrict__ A,
                                               const short* __restrict__ Bt,
                                               float* __restrict__ C,
                                               int M, int N, int K) {
  const int tid  = threadIdx.x;
  const int m0   = blockIdx.y * 64;
  const int n0   = blockIdx.x * 64;
  const int wave = tid >> 6, lane = tid & 63;
  const int quad = lane >> 4, l16 = lane & 15;
  const int wm   = (wave >> 1) * 32, wn = (wave & 1) * 32;

  __shared__ short As[64 * 72];
  __shared__ short Bs[64 * 72];

  const f32x4 z = {0.f, 0.f, 0.f, 0.f};
  f32x4 acc[2][2] = {{z, z}, {z, z}};

  for (int k0 = 0; k0 < K; k0 += 64) {
#pragma unroll
    for (int i = 0; i < 2; i++) {
      int idx = tid + i * 256;        // 0..511
      int r   = idx >> 3;             // 64 rows, 8 x 16B chunks each
      int c8  = idx & 7;
      *(i32x4*)&As[r * 72 + c8 * 8] = *(const i32x4*)&A [(size_t)(m0 + r) * K + k0 + c8 * 8];
      *(i32x4*)&Bs[r * 72 + c8 * 8] = *(const i32x4*)&Bt[(size_t)(n0 + r) * K + k0 + c8 * 8];
    }
    __syncthreads();
#pragma unroll
    for (int ks = 0; ks < 64; ks += 32) {
      bf16x8 a0 = *(const bf16x8*)&As[(wm +      l16) * 72 + ks + quad * 8];
      bf16x8 a1 = *(const bf16x8*)&As[(wm + 16 + l16) * 72 + ks + quad * 8];
      bf16x8 b0 = *(const bf16x8*)&Bs[(wn +      l16) * 72 + ks + quad * 8];
      bf16x8 b1 = *(const bf16x8*)&Bs[(wn + 16 + l16) * 72 + ks + quad * 8];
      acc[0][0] = __builtin_amdgcn_mfma_f32_16x16x32_bf16(a0, b0, acc[0][0], 0, 0, 0);
      acc[0][1] = __builtin_amdgcn_mfma_f32_16x16x32_bf16(a0, b1, acc[0][1], 0, 0, 0);
      acc[1][0] = __builtin_amdgcn_mfma_f32_16x16x32_bf16(a1, b0, acc[1][0], 0, 0, 0);
      acc[1][1] = __builtin_amdgcn_mfma_f32_16x16x32_bf16(a1, b1, acc[1][1], 0, 0, 0);
    }
    __syncthreads();
  }

  // C/D layout: col = lane&15, row = quad*4 + reg  [verified m89/m91]
#pragma unroll
  for (int i = 0; i < 2; i++)
#pragma unroll
    for (int j = 0; j < 2; j++) {
      int r0 = m0 + wm + 16 * i + quad * 4;
      int c  = n0 + wn + 16 * j + l16;
#pragma unroll
      for (int r = 0; r < 4; r++)
        C[(size_t)(r0 + r) * N + c] = acc[i][j][r];
    }
}

// ---------------------------------------------------------------- RMSNorm + RoPE; q -> Qb bf16 (pre-scaled), k -> Kb bf16
__global__ __launch_bounds__(64) void rmsnorm_rope_qk(const float* __restrict__ qkv,
                                                      const float* __restrict__ cosT,
                                                      const float* __restrict__ sinT,
                                                      const float* __restrict__ qw,
                                                      const float* __restrict__ kw,
                                                      short* __restrict__ Qb,
                                                      short* __restrict__ Kb) {
  int t    = blockIdx.x;        // token 0..2047
  int hd   = blockIdx.y;        // 0..35: 0..31 q-heads, 32..35 k-heads
  int b    = t >> 10;
  int s    = t & (S_ - 1);
  int lane = threadIdx.x;       // 0..63; owns d=lane and d=lane+64
  const float QSC = 0.08838834764831845f * 1.4426950408889634f;  // SCALE*log2(e)
  const float* base;
  const float* w;
  short* dst;
  float osc;
  if (hd < H_) {
    base = qkv + (size_t)t * NQKV + hd * D_;
    w = qw; osc = QSC;
    dst = Qb + (((size_t)b * H_ + hd) * S_ + s) * D_;
  } else {
    base = qkv + (size_t)t * NQKV + H_ * D_ + (hd - H_) * D_;
    w = kw; osc = 1.0f;
    dst = Kb + (((size_t)b * HK_ + (hd - H_)) * S_ + s) * D_;
  }
  float x1 = base[lane], x2 = base[lane + 64];
  float ss = x1 * x1 + x2 * x2;
#pragma unroll
  for (int off = 32; off > 0; off >>= 1) ss += __shfl_xor(ss, off, 64);
  float rn = rsqrtf(ss * (1.0f / 128.0f) + 1e-6f);
  float y1 = x1 * rn * w[lane], y2 = x2 * rn * w[lane + 64];
  float c1 = cosT[s * D_ + lane],      s1 = sinT[s * D_ + lane];
  float c2 = cosT[s * D_ + lane + 64], s2 = sinT[s * D_ + lane + 64];
  dst[lane]      = f2bf((y1 * c1 - y2 * s1) * osc);   // rotate_half
  dst[lane + 64] = f2bf((y2 * c2 + y1 * s2) * osc);
}

// ---------------------------------------------------------------- V: fp32 qkv slice -> bf16 transposed [b][kh][D][S]
__global__ __launch_bounds__(256) void v_pack(const float* __restrict__ qkv,
                                              short* __restrict__ Vt) {
  int bk = blockIdx.x;            // 0..7 = b*HK+kh
  int s0 = blockIdx.y * 64;
  int d  = threadIdx.x & 127;
  int sg = threadIdx.x >> 7;      // 0..1
  int b = bk >> 2, kh = bk & 3;
  short buf[32];
  const float* src = qkv + ((size_t)(b * S_ + s0 + sg * 32)) * NQKV + (H_ + HK_) * D_ + kh * D_ + d;
#pragma unroll
  for (int sj = 0; sj < 32; sj++)
    buf[sj] = f2bf(src[(size_t)sj * NQKV]);
  short* dst = Vt + ((size_t)bk * D_ + d) * S_ + s0 + sg * 32;
#pragma unroll
  for (int i = 0; i < 4; i++) ((i32x4*)dst)[i] = ((const i32x4*)buf)[i];
}

// ---------------------------------------------------------------- MFMA flash attention (causal GQA), writes bf16 ctx
__global__ __launch_bounds__(256) void attn_mfma(const short* __restrict__ Qb,
                                                 const short* __restrict__ Kb,
                                                 const short* __restrict__ Vt,
                                                 short* __restrict__ ctx) {
  const int qt = blockIdx.x;      // q tile (64 rows)
  const int h  = blockIdx.y;
  const int b  = blockIdx.z;
  const int kh = h >> 3;          // G = 8
  const int q0 = qt * 64;
  const int tid = threadIdx.x, w = tid >> 6, lane = tid & 63;
  const int quad = lane >> 4, l16 = lane & 15;

  __shared__ short Ks[64 * 136];       // K tile [key][d], also Q staging
  __shared__ short Vs[128 * 72];       // V^T tile [d][key]
  __shared__ short Ps[4][16 * 72];     // per-wave P [qrow][key]

  // ---- stage Q through Ks, pull A-frags to registers
  const short* Qbase = Qb + (((size_t)b * H_ + h) * S_ + q0) * D_;
#pragma unroll
  for (int i = 0; i < 4; i++) {
    int idx = tid + i * 256;           // 64 rows x 16 chunks of 16B
    int r = idx >> 4, c = idx & 15;
    *(i32x4*)&Ks[r * 136 + c * 8] = *(const i32x4*)&Qbase[(size_t)r * D_ + c * 8];
  }
  __syncthreads();
  bf16x8 aq[4];
#pragma unroll
  for (int kb = 0; kb < 4; kb++)
    aq[kb] = *(const bf16x8*)&Ks[(w * 16 + l16) * 136 + kb * 32 + quad * 8];
  __syncthreads();

  const f32x4 z = {0.f, 0.f, 0.f, 0.f};
  f32x4 O[8] = {z, z, z, z, z, z, z, z};
  float m_r[4] = {-1e30f, -1e30f, -1e30f, -1e30f};
  float l_r[4] = {0.f, 0.f, 0.f, 0.f};

  const short* Kbase = Kb + ((size_t)(b * HK_ + kh) * S_) * D_;
  const short* Vbase = Vt + ((size_t)(b * HK_ + kh) * D_) * S_;

  for (int kt = 0; kt <= qt; kt++) {
    const int k0 = kt * 64;
    // stage K tile: 64 rows x 16 chunks
#pragma unroll
    for (int i = 0; i < 4; i++) {
      int idx = tid + i * 256;
      int r = idx >> 4, c = idx & 15;
      *(i32x4*)&Ks[r * 136 + c * 8] = *(const i32x4*)&Kbase[(size_t)(k0 + r) * D_ + c * 8];
    }
    // stage V^T tile: 128 rows x 8 chunks
#pragma unroll
    for (int i = 0; i < 4; i++) {
      int idx = tid + i * 256;
      int r = idx >> 3, c = idx & 7;
      *(i32x4*)&Vs[r * 72 + c * 8] = *(const i32x4*)&Vbase[(size_t)r * S_ + k0 + c * 8];
    }
    __syncthreads();

    // ---- QK^T: Sc[nb] = 16x16 tile, cols k0+nb*16+l16, rows q0+w*16+quad*4+r
    f32x4 Sc[4] = {z, z, z, z};
#pragma unroll
    for (int kb = 0; kb < 4; kb++) {
#pragma unroll
      for (int nb = 0; nb < 4; nb++) {
        bf16x8 bk = *(const bf16x8*)&Ks[(nb * 16 + l16) * 136 + kb * 32 + quad * 8];
        Sc[nb] = __builtin_amdgcn_mfma_f32_16x16x32_bf16(aq[kb], bk, Sc[nb], 0, 0, 0);
      }
    }
    if (kt == qt) {   // causal mask on the diagonal tile
#pragma unroll
      for (int nb = 0; nb < 4; nb++) {
        int col = k0 + nb * 16 + l16;
#pragma unroll
        for (int r = 0; r < 4; r++) {
          int row = q0 + w * 16 + quad * 4 + r;
          if (col > row) Sc[nb][r] = -1e30f;
        }
      }
    }

    // ---- online softmax, per row (quad*4+r), reduce across l16 lanes
    float alpha[4];
#pragma unroll
    for (int r = 0; r < 4; r++) {
      float mx = fmaxf(fmaxf(Sc[0][r], Sc[1][r]), fmaxf(Sc[2][r], Sc[3][r]));
#pragma unroll
      for (int off = 1; off < 16; off <<= 1) mx = fmaxf(mx, __shfl_xor(mx, off, 64));
      float mn = fmaxf(m_r[r], mx);
      alpha[r] = exp2f(m_r[r] - mn);
      m_r[r] = mn;
      float sum = 0.f;
#pragma unroll
      for (int nb = 0; nb < 4; nb++) {
        float p = exp2f(Sc[nb][r] - mn);
        Sc[nb][r] = p;
        sum += p;
      }
#pragma unroll
      for (int off = 1; off < 16; off <<= 1) sum += __shfl_xor(sum, off, 64);
      l_r[r] = l_r[r] * alpha[r] + sum;
    }

    // ---- P (C-layout) -> LDS bf16, per-wave region
#pragma unroll
    for (int nb = 0; nb < 4; nb++)
#pragma unroll
      for (int r = 0; r < 4; r++)
        Ps[w][(quad * 4 + r) * 72 + nb * 16 + l16] = f2bf(Sc[nb][r]);

    // ---- rescale O
#pragma unroll
    for (int nb2 = 0; nb2 < 8; nb2++)
#pragma unroll
      for (int r = 0; r < 4; r++) O[nb2][r] *= alpha[r];

    // ---- PV: A = P [qrow][key], B = V^T [d][key]
#pragma unroll
    for (int kb2 = 0; kb2 < 2; kb2++) {
      bf16x8 ap = *(const bf16x8*)&Ps[w][l16 * 72 + kb2 * 32 + quad * 8];
#pragma unroll
      for (int nb2 = 0; nb2 < 8; nb2++) {
        bf16x8 bv = *(const bf16x8*)&Vs[(nb2 * 16 + l16) * 72 + kb2 * 32 + quad * 8];
        O[nb2] = __builtin_amdgcn_mfma_f32_16x16x32_bf16(ap, bv, O[nb2], 0, 0, 0);
      }
    }
    __syncthreads();   // protect Ks/Vs before next stage
  }

  // ---- epilogue: O/l -> ctx bf16 [b][s][h*D]
#pragma unroll
  for (int r = 0; r < 4; r++) {
    float inv = 1.0f / l_r[r];
    size_t row = (size_t)(b * S_ + q0 + w * 16 + quad * 4 + r);
    short* dst = ctx + row * (H_ * D_) + h * D_;
#pragma unroll
    for (int nb2 = 0; nb2 < 8; nb2++)
      dst[nb2 * 16 + l16] = f2bf(O[nb2][r] * inv);
  }
}

// ---------------------------------------------------------------- launch
extern "C" void kernel_launch(void* const* d_in, const int* in_sizes, int n_in,
                              void* d_out, int out_size, void* d_ws, size_t ws_size,
                              hipStream_t stream) {
  (void)in_sizes; (void)n_in; (void)out_size; (void)ws_size;
  const float* hidden = (const float*)d_in[0];
  const float* cosT   = (const float*)d_in[1];
  const float* sinT   = (const float*)d_in[2];
  const float* wqkv   = (const float*)d_in[3];
  const float* qnw    = (const float*)d_in[4];
  const float* knw    = (const float*)d_in[5];
  const float* wo     = (const float*)d_in[6];
  float* out = (float*)d_out;

  char* ws = (char*)d_ws;
  float* qkv = (float*)(ws);                                  // 2048*5120 f32  = 41,943,040 B
  short* hb  = (short*)(ws + 41943040);                       // 8 MB: hidden bf16 (dead after gemm1)
  short* wT  = (short*)(ws + 41943040 + 8388608);             // 20 MB: w bf16^T (gemm1), then Qb, then w_o^T
  short* ctx = (short*)(ws + 41943040 + 8388608 + 20971520);  // 16 MB: ctx bf16
  // aliases (stream-ordered reuse):
  short* Kb  = hb;                                            // 2 MB, written after gemm1 done with hb
  short* Vt  = hb + 1048576;                                  // 2 MB
  short* Qb  = wT;                                            // 16 MB <= 20 MB, written after gemm1 done with wT
  // total ws = 88,080,384 B (same as round 1)

  // 1. hidden -> bf16
  cast_f32_bf16<<<4096, 256, 0, stream>>>(hidden, hb, TOK * HID_ / 4);
  // 2. w_qkv [2048][5120] -> bf16 [5120][2048]
  transpose_cast<<<dim3(NQKV / 32, HID_ / 32), 256, 0, stream>>>(wqkv, wT, HID_, NQKV);
  // 3. qkv = hidden @ w_qkv   (M=2048, N=5120, K=2048)
  gemm_bt<<<dim3(NQKV / 64, TOK / 64), 256, 0, stream>>>(hb, wT, qkv, TOK, NQKV, HID_);
  // 4. RMSNorm + RoPE -> Qb (pre-scaled bf16), Kb (bf16)   [clobbers wT/hb — gemm1 done]
  rmsnorm_rope_qk<<<dim3(TOK, H_ + HK_), 64, 0, stream>>>(qkv, cosT, sinT, qnw, knw, Qb, Kb);
  // 5. V slice -> bf16 transposed [b][kh][D][S]
  v_pack<<<dim3(B_ * HK_, S_ / 64), 256, 0, stream>>>(qkv, Vt);
  // 6. MFMA causal GQA flash attention -> ctx bf16 [2048][4096]
  attn_mfma<<<dim3(S_ / 64, H_, B_), 256, 0, stream>>>(Qb, Kb, Vt, ctx);
  // 7. w_o [4096][2048] -> bf16 [2048][4096]   [clobbers Qb — attention done]
  transpose_cast<<<dim3(HID_ / 32, (H_ * D_) / 32), 256, 0, stream>>>(wo, wT, H_ * D_, HID_);
  // 8. out = ctx @ w_o   (M=2048, N=2048, K=4096)
  gemm_bt<<<dim3(HID_ / 64, TOK / 64), 256, 0, stream>>>(ctx, wT, out, TOK, HID_, H_ * D_);
}

// Round 3
// 410.577 us; speedup vs baseline: 2.9746x; 1.1258x over previous
//
#include <hip/hip_runtime.h>

// Problem constants (Qwen3MoE attention prefill)
#define B_   2
#define S_   1024
#define HID_ 2048
#define H_   32
#define HK_  4
#define D_   128
#define NQKV ((H_ + 2 * HK_) * D_)   // 5120
#define TOK  (B_ * S_)               // 2048

typedef short bf16x8  __attribute__((ext_vector_type(8)));  // 8 bf16 (4 VGPRs)
typedef short short4v __attribute__((ext_vector_type(4)));
typedef float f32x4   __attribute__((ext_vector_type(4)));
typedef int   i32x4   __attribute__((ext_vector_type(4)));

__device__ inline short f2bf(float f) {
  unsigned u = __builtin_bit_cast(unsigned, f);
  u += 0x7fffu + ((u >> 16) & 1u);   // round-to-nearest-even
  return (short)(u >> 16);
}

// async global->LDS, 16B per lane; LDS dest must be wave-uniform base (lane*16 implicit)
__device__ __forceinline__ void gld_lds16(const short* g, short* l) {
  __builtin_amdgcn_global_load_lds((__attribute__((address_space(1))) void*)g,
                                   (__attribute__((address_space(3))) void*)l, 16, 0, 0);
}

// ---------------------------------------------------------------- cast fp32 -> bf16
__global__ __launch_bounds__(256) void cast_f32_bf16(const float* __restrict__ in,
                                                     short* __restrict__ out, int n4) {
  int i = blockIdx.x * 256 + threadIdx.x;
  if (i >= n4) return;
  f32x4 v = ((const f32x4*)in)[i];
  short4v o;
  o[0] = f2bf(v[0]); o[1] = f2bf(v[1]); o[2] = f2bf(v[2]); o[3] = f2bf(v[3]);
  ((short4v*)out)[i] = o;
}

// ---------------------------------------------------------------- transpose+cast: [K][N] f32 -> [N][K] bf16
__global__ __launch_bounds__(256) void transpose_cast(const float* __restrict__ in,
                                                      short* __restrict__ out,
                                                      int K, int N) {
  __shared__ float tile[32][33];
  int nb = blockIdx.x * 32, kb = blockIdx.y * 32;
  int c = threadIdx.x & 31, r0 = threadIdx.x >> 5;  // 8 rows per pass
#pragma unroll
  for (int i = 0; i < 4; i++) {
    int r = r0 + i * 8;
    tile[r][c] = in[(size_t)(kb + r) * N + nb + c];
  }
  __syncthreads();
#pragma unroll
  for (int i = 0; i < 4; i++) {
    int r = r0 + i * 8;
    out[(size_t)(nb + r) * K + kb + c] = f2bf(tile[c][r]);
  }
}

// ---------------------------------------------------------------- bf16 MFMA GEMM (m97 structure):
// C = A[M][K] * Bt[N][K]^T, fp32 out. 128x128 tile, BK=64, global_load_lds(16) staging,
// XOR chunk swizzle: LDS physical chunk c holds logical chunk c^(row&7) -> ds_read_b128
// fragment reads hit all 32 banks at 2-way (free, m136) with zero padding.
__global__ __launch_bounds__(256) void gemm_bt128(const short* __restrict__ A,
                                                  const short* __restrict__ Bt,
                                                  float* __restrict__ C,
                                                  int M, int N, int K) {
  const int tid  = threadIdx.x;
  const int m0   = blockIdx.y * 128;
  const int n0   = blockIdx.x * 128;
  const int w    = tid >> 6, lane = tid & 63;
  const int quad = lane >> 4, l16 = lane & 15;
  const int wm   = (w >> 1) * 64, wn = (w & 1) * 64;

  __shared__ short As[128 * 64];   // 16 KB, row-major [row][64], chunks XOR-swizzled
  __shared__ short Bs[128 * 64];

  const f32x4 z = {0.f, 0.f, 0.f, 0.f};
  f32x4 acc[4][4];
#pragma unroll
  for (int i = 0; i < 4; i++)
#pragma unroll
    for (int j = 0; j < 4; j++) acc[i][j] = z;

  // staging lane geometry: one issue = 8 rows x 8 chunks (64 lanes x 16B)
  const int srow = lane >> 3;           // row within issue group
  const int lc   = (lane & 7) ^ srow;   // logical chunk this lane fetches

  for (int k0 = 0; k0 < K; k0 += 64) {
#pragma unroll
    for (int i = 0; i < 4; i++) {
      int rb = w * 32 + i * 8;          // wave-uniform row base
      gld_lds16(&A [(size_t)(m0 + rb + srow) * K + k0 + lc * 8], &As[rb * 64]);
      gld_lds16(&Bt[(size_t)(n0 + rb + srow) * K + k0 + lc * 8], &Bs[rb * 64]);
    }
    __syncthreads();
#pragma unroll
    for (int kb = 0; kb < 2; kb++) {
      const int pc = ((kb * 4 + quad) ^ (l16 & 7)) * 8;  // physical chunk offset
      bf16x8 a[4], b[4];
#pragma unroll
      for (int f = 0; f < 4; f++) {
        a[f] = *(const bf16x8*)&As[(wm + f * 16 + l16) * 64 + pc];
        b[f] = *(const bf16x8*)&Bs[(wn + f * 16 + l16) * 64 + pc];
      }
#pragma unroll
      for (int fi = 0; fi < 4; fi++)
#pragma unroll
        for (int fj = 0; fj < 4; fj++)
          acc[fi][fj] = __builtin_amdgcn_mfma_f32_16x16x32_bf16(a[fi], b[fj], acc[fi][fj], 0, 0, 0);
    }
    __syncthreads();
  }

  // C/D layout: col = lane&15, row = quad*4 + reg  [verified m89/m91]
#pragma unroll
  for (int fi = 0; fi < 4; fi++) {
    int row0 = m0 + wm + fi * 16 + quad * 4;
#pragma unroll
    for (int fj = 0; fj < 4; fj++) {
      int col = n0 + wn + fj * 16 + l16;
#pragma unroll
      for (int r = 0; r < 4; r++)
        C[(size_t)(row0 + r) * N + col] = acc[fi][fj][r];
    }
  }
}

// ---------------------------------------------------------------- RMSNorm + RoPE; q -> Qb bf16 (pre-scaled), k -> Kb bf16
__global__ __launch_bounds__(64) void rmsnorm_rope_qk(const float* __restrict__ qkv,
                                                      const float* __restrict__ cosT,
                                                      const float* __restrict__ sinT,
                                                      const float* __restrict__ qw,
                                                      const float* __restrict__ kw,
                                                      short* __restrict__ Qb,
                                                      short* __restrict__ Kb) {
  int t    = blockIdx.x;        // token 0..2047
  int hd   = blockIdx.y;        // 0..35: 0..31 q-heads, 32..35 k-heads
  int b    = t >> 10;
  int s    = t & (S_ - 1);
  int lane = threadIdx.x;       // 0..63; owns d=lane and d=lane+64
  const float QSC = 0.08838834764831845f * 1.4426950408889634f;  // SCALE*log2(e)
  const float* base;
  const float* w;
  short* dst;
  float osc;
  if (hd < H_) {
    base = qkv + (size_t)t * NQKV + hd * D_;
    w = qw; osc = QSC;
    dst = Qb + (((size_t)b * H_ + hd) * S_ + s) * D_;
  } else {
    base = qkv + (size_t)t * NQKV + H_ * D_ + (hd - H_) * D_;
    w = kw; osc = 1.0f;
    dst = Kb + (((size_t)b * HK_ + (hd - H_)) * S_ + s) * D_;
  }
  float x1 = base[lane], x2 = base[lane + 64];
  float ss = x1 * x1 + x2 * x2;
#pragma unroll
  for (int off = 32; off > 0; off >>= 1) ss += __shfl_xor(ss, off, 64);
  float rn = rsqrtf(ss * (1.0f / 128.0f) + 1e-6f);
  float y1 = x1 * rn * w[lane], y2 = x2 * rn * w[lane + 64];
  float c1 = cosT[s * D_ + lane],      s1 = sinT[s * D_ + lane];
  float c2 = cosT[s * D_ + lane + 64], s2 = sinT[s * D_ + lane + 64];
  dst[lane]      = f2bf((y1 * c1 - y2 * s1) * osc);   // rotate_half
  dst[lane + 64] = f2bf((y2 * c2 + y1 * s2) * osc);
}

// ---------------------------------------------------------------- V: fp32 qkv slice -> bf16 transposed [b][kh][D][S]
__global__ __launch_bounds__(256) void v_pack(const float* __restrict__ qkv,
                                              short* __restrict__ Vt) {
  int bk = blockIdx.x;            // 0..7 = b*HK+kh
  int s0 = blockIdx.y * 64;
  int d  = threadIdx.x & 127;
  int sg = threadIdx.x >> 7;      // 0..1
  int b = bk >> 2, kh = bk & 3;
  short buf[32];
  const float* src = qkv + ((size_t)(b * S_ + s0 + sg * 32)) * NQKV + (H_ + HK_) * D_ + kh * D_ + d;
#pragma unroll
  for (int sj = 0; sj < 32; sj++)
    buf[sj] = f2bf(src[(size_t)sj * NQKV]);
  short* dst = Vt + ((size_t)bk * D_ + d) * S_ + s0 + sg * 32;
#pragma unroll
  for (int i = 0; i < 4; i++) ((i32x4*)dst)[i] = ((const i32x4*)buf)[i];
}

// ---------------------------------------------------------------- MFMA flash attention (causal GQA), writes bf16 ctx
__global__ __launch_bounds__(256) void attn_mfma(const short* __restrict__ Qb,
                                                 const short* __restrict__ Kb,
                                                 const short* __restrict__ Vt,
                                                 short* __restrict__ ctx) {
  const int qt = blockIdx.x;      // q tile (64 rows)
  const int h  = blockIdx.y;
  const int b  = blockIdx.z;
  const int kh = h >> 3;          // G = 8
  const int q0 = qt * 64;
  const int tid = threadIdx.x, w = tid >> 6, lane = tid & 63;
  const int quad = lane >> 4, l16 = lane & 15;

  __shared__ short Ks[64 * 136];       // K tile [key][d], also Q staging
  __shared__ short Vs[128 * 72];       // V^T tile [d][key]
  __shared__ short Ps[4][16 * 72];     // per-wave P [qrow][key]

  // ---- stage Q through Ks, pull A-frags to registers
  const short* Qbase = Qb + (((size_t)b * H_ + h) * S_ + q0) * D_;
#pragma unroll
  for (int i = 0; i < 4; i++) {
    int idx = tid + i * 256;           // 64 rows x 16 chunks of 16B
    int r = idx >> 4, c = idx & 15;
    *(i32x4*)&Ks[r * 136 + c * 8] = *(const i32x4*)&Qbase[(size_t)r * D_ + c * 8];
  }
  __syncthreads();
  bf16x8 aq[4];
#pragma unroll
  for (int kb = 0; kb < 4; kb++)
    aq[kb] = *(const bf16x8*)&Ks[(w * 16 + l16) * 136 + kb * 32 + quad * 8];
  __syncthreads();

  const f32x4 z = {0.f, 0.f, 0.f, 0.f};
  f32x4 O[8] = {z, z, z, z, z, z, z, z};
  float m_r[4] = {-1e30f, -1e30f, -1e30f, -1e30f};
  float l_r[4] = {0.f, 0.f, 0.f, 0.f};

  const short* Kbase = Kb + ((size_t)(b * HK_ + kh) * S_) * D_;
  const short* Vbase = Vt + ((size_t)(b * HK_ + kh) * D_) * S_;

  for (int kt = 0; kt <= qt; kt++) {
    const int k0 = kt * 64;
    // stage K tile: 64 rows x 16 chunks
#pragma unroll
    for (int i = 0; i < 4; i++) {
      int idx = tid + i * 256;
      int r = idx >> 4, c = idx & 15;
      *(i32x4*)&Ks[r * 136 + c * 8] = *(const i32x4*)&Kbase[(size_t)(k0 + r) * D_ + c * 8];
    }
    // stage V^T tile: 128 rows x 8 chunks
#pragma unroll
    for (int i = 0; i < 4; i++) {
      int idx = tid + i * 256;
      int r = idx >> 3, c = idx & 7;
      *(i32x4*)&Vs[r * 72 + c * 8] = *(const i32x4*)&Vbase[(size_t)r * S_ + k0 + c * 8];
    }
    __syncthreads();

    // ---- QK^T: Sc[nb] = 16x16 tile, cols k0+nb*16+l16, rows q0+w*16+quad*4+r
    f32x4 Sc[4] = {z, z, z, z};
#pragma unroll
    for (int kb = 0; kb < 4; kb++) {
#pragma unroll
      for (int nb = 0; nb < 4; nb++) {
        bf16x8 bk = *(const bf16x8*)&Ks[(nb * 16 + l16) * 136 + kb * 32 + quad * 8];
        Sc[nb] = __builtin_amdgcn_mfma_f32_16x16x32_bf16(aq[kb], bk, Sc[nb], 0, 0, 0);
      }
    }
    if (kt == qt) {   // causal mask on the diagonal tile
#pragma unroll
      for (int nb = 0; nb < 4; nb++) {
        int col = k0 + nb * 16 + l16;
#pragma unroll
        for (int r = 0; r < 4; r++) {
          int row = q0 + w * 16 + quad * 4 + r;
          if (col > row) Sc[nb][r] = -1e30f;
        }
      }
    }

    // ---- online softmax, per row (quad*4+r), reduce across l16 lanes
    float alpha[4];
#pragma unroll
    for (int r = 0; r < 4; r++) {
      float mx = fmaxf(fmaxf(Sc[0][r], Sc[1][r]), fmaxf(Sc[2][r], Sc[3][r]));
#pragma unroll
      for (int off = 1; off < 16; off <<= 1) mx = fmaxf(mx, __shfl_xor(mx, off, 64));
      float mn = fmaxf(m_r[r], mx);
      alpha[r] = exp2f(m_r[r] - mn);
      m_r[r] = mn;
      float sum = 0.f;
#pragma unroll
      for (int nb = 0; nb < 4; nb++) {
        float p = exp2f(Sc[nb][r] - mn);
        Sc[nb][r] = p;
        sum += p;
      }
#pragma unroll
      for (int off = 1; off < 16; off <<= 1) sum += __shfl_xor(sum, off, 64);
      l_r[r] = l_r[r] * alpha[r] + sum;
    }

    // ---- P (C-layout) -> LDS bf16, per-wave region
#pragma unroll
    for (int nb = 0; nb < 4; nb++)
#pragma unroll
      for (int r = 0; r < 4; r++)
        Ps[w][(quad * 4 + r) * 72 + nb * 16 + l16] = f2bf(Sc[nb][r]);

    // ---- rescale O
#pragma unroll
    for (int nb2 = 0; nb2 < 8; nb2++)
#pragma unroll
      for (int r = 0; r < 4; r++) O[nb2][r] *= alpha[r];

    // ---- PV: A = P [qrow][key], B = V^T [d][key]
#pragma unroll
    for (int kb2 = 0; kb2 < 2; kb2++) {
      bf16x8 ap = *(const bf16x8*)&Ps[w][l16 * 72 + kb2 * 32 + quad * 8];
#pragma unroll
      for (int nb2 = 0; nb2 < 8; nb2++) {
        bf16x8 bv = *(const bf16x8*)&Vs[(nb2 * 16 + l16) * 72 + kb2 * 32 + quad * 8];
        O[nb2] = __builtin_amdgcn_mfma_f32_16x16x32_bf16(ap, bv, O[nb2], 0, 0, 0);
      }
    }
    __syncthreads();   // protect Ks/Vs before next stage
  }

  // ---- epilogue: O/l -> ctx bf16 [b][s][h*D]
#pragma unroll
  for (int r = 0; r < 4; r++) {
    float inv = 1.0f / l_r[r];
    size_t row = (size_t)(b * S_ + q0 + w * 16 + quad * 4 + r);
    short* dst = ctx + row * (H_ * D_) + h * D_;
#pragma unroll
    for (int nb2 = 0; nb2 < 8; nb2++)
      dst[nb2 * 16 + l16] = f2bf(O[nb2][r] * inv);
  }
}

// ---------------------------------------------------------------- launch
extern "C" void kernel_launch(void* const* d_in, const int* in_sizes, int n_in,
                              void* d_out, int out_size, void* d_ws, size_t ws_size,
                              hipStream_t stream) {
  (void)in_sizes; (void)n_in; (void)out_size; (void)ws_size;
  const float* hidden = (const float*)d_in[0];
  const float* cosT   = (const float*)d_in[1];
  const float* sinT   = (const float*)d_in[2];
  const float* wqkv   = (const float*)d_in[3];
  const float* qnw    = (const float*)d_in[4];
  const float* knw    = (const float*)d_in[5];
  const float* wo     = (const float*)d_in[6];
  float* out = (float*)d_out;

  char* ws = (char*)d_ws;
  float* qkv = (float*)(ws);                                  // 2048*5120 f32  = 41,943,040 B
  short* hb  = (short*)(ws + 41943040);                       // 8 MB: hidden bf16 (dead after gemm1)
  short* wT  = (short*)(ws + 41943040 + 8388608);             // 20 MB: w bf16^T (gemm1), then Qb, then w_o^T
  short* ctx = (short*)(ws + 41943040 + 8388608 + 20971520);  // 16 MB: ctx bf16
  // aliases (stream-ordered reuse):
  short* Kb  = hb;                                            // 2 MB, written after gemm1 done with hb
  short* Vt  = hb + 1048576;                                  // 2 MB
  short* Qb  = wT;                                            // 16 MB <= 20 MB, written after gemm1 done with wT
  // total ws = 88,080,384 B (same as round 1)

  // 1. hidden -> bf16
  cast_f32_bf16<<<4096, 256, 0, stream>>>(hidden, hb, TOK * HID_ / 4);
  // 2. w_qkv [2048][5120] -> bf16 [5120][2048]
  transpose_cast<<<dim3(NQKV / 32, HID_ / 32), 256, 0, stream>>>(wqkv, wT, HID_, NQKV);
  // 3. qkv = hidden @ w_qkv   (M=2048, N=5120, K=2048)
  gemm_bt128<<<dim3(NQKV / 128, TOK / 128), 256, 0, stream>>>(hb, wT, qkv, TOK, NQKV, HID_);
  // 4. RMSNorm + RoPE -> Qb (pre-scaled bf16), Kb (bf16)   [clobbers wT/hb — gemm1 done]
  rmsnorm_rope_qk<<<dim3(TOK, H_ + HK_), 64, 0, stream>>>(qkv, cosT, sinT, qnw, knw, Qb, Kb);
  // 5. V slice -> bf16 transposed [b][kh][D][S]
  v_pack<<<dim3(B_ * HK_, S_ / 64), 256, 0, stream>>>(qkv, Vt);
  // 6. MFMA causal GQA flash attention -> ctx bf16 [2048][4096]
  attn_mfma<<<dim3(S_ / 64, H_, B_), 256, 0, stream>>>(Qb, Kb, Vt, ctx);
  // 7. w_o [4096][2048] -> bf16 [2048][4096]   [clobbers Qb — attention done]
  transpose_cast<<<dim3(HID_ / 32, (H_ * D_) / 32), 256, 0, stream>>>(wo, wT, H_ * D_, HID_);
  // 8. out = ctx @ w_o   (M=2048, N=2048, K=4096)
  gemm_bt128<<<dim3(HID_ / 128, TOK / 128), 256, 0, stream>>>(ctx, wT, out, TOK, HID_, H_ * D_);
}

// Round 4
// 366.089 us; speedup vs baseline: 3.3360x; 1.1215x over previous
//
#include <hip/hip_runtime.h>

// Problem constants (Qwen3MoE attention prefill)
#define B_   2
#define S_   1024
#define HID_ 2048
#define H_   32
#define HK_  4
#define D_   128
#define NQKV ((H_ + 2 * HK_) * D_)   // 5120
#define TOK  (B_ * S_)               // 2048

typedef short bf16x8  __attribute__((ext_vector_type(8)));  // 8 bf16 (4 VGPRs)
typedef short short4v __attribute__((ext_vector_type(4)));
typedef float f32x4   __attribute__((ext_vector_type(4)));
typedef int   i32x4   __attribute__((ext_vector_type(4)));

__device__ inline short f2bf(float f) {
  unsigned u = __builtin_bit_cast(unsigned, f);
  u += 0x7fffu + ((u >> 16) & 1u);   // round-to-nearest-even
  return (short)(u >> 16);
}

// async global->LDS, 16B per lane; LDS dest is wave-uniform base + lane*16
__device__ __forceinline__ void gld_lds16(const short* g, short* l) {
  __builtin_amdgcn_global_load_lds((__attribute__((address_space(1))) void*)g,
                                   (__attribute__((address_space(3))) void*)l, 16, 0, 0);
}

// ---------------------------------------------------------------- cast fp32 -> bf16
__global__ __launch_bounds__(256) void cast_f32_bf16(const float* __restrict__ in,
                                                     short* __restrict__ out, int n4) {
  int i = blockIdx.x * 256 + threadIdx.x;
  if (i >= n4) return;
  f32x4 v = ((const f32x4*)in)[i];
  short4v o;
  o[0] = f2bf(v[0]); o[1] = f2bf(v[1]); o[2] = f2bf(v[2]); o[3] = f2bf(v[3]);
  ((short4v*)out)[i] = o;
}

// ---------------------------------------------------------------- transpose+cast: [K][N] f32 -> [N][K] bf16
__global__ __launch_bounds__(256) void transpose_cast(const float* __restrict__ in,
                                                      short* __restrict__ out,
                                                      int K, int N) {
  __shared__ float tile[32][33];
  int nb = blockIdx.x * 32, kb = blockIdx.y * 32;
  int c = threadIdx.x & 31, r0 = threadIdx.x >> 5;
#pragma unroll
  for (int i = 0; i < 4; i++) {
    int r = r0 + i * 8;
    tile[r][c] = in[(size_t)(kb + r) * N + nb + c];
  }
  __syncthreads();
#pragma unroll
  for (int i = 0; i < 4; i++) {
    int r = r0 + i * 8;
    out[(size_t)(nb + r) * K + kb + c] = f2bf(tile[c][r]);
  }
}

// ---------------------------------------------------------------- bf16 MFMA GEMM (m97 structure), split-K capable:
// C[kz] = A[M][Kfull](cols k0..k0+klen) * Bt[N][Kfull]^T, k0 = blockIdx.z*klen.
// Partial outputs go to C + kz*M*N (kz>0 requires a reduce pass).
__global__ __launch_bounds__(256) void gemm_bt128(const short* __restrict__ A,
                                                  const short* __restrict__ Bt,
                                                  float* __restrict__ C,
                                                  int M, int N, int Kfull, int klen) {
  const int tid  = threadIdx.x;
  const int m0   = blockIdx.y * 128;
  const int n0   = blockIdx.x * 128;
  const int kz0  = blockIdx.z * klen;
  const int w    = tid >> 6, lane = tid & 63;
  const int quad = lane >> 4, l16 = lane & 15;
  const int wm   = (w >> 1) * 64, wn = (w & 1) * 64;

  __shared__ short As[128 * 64];   // 16 KB, [row][64], chunks XOR-swizzled
  __shared__ short Bs[128 * 64];

  const f32x4 z = {0.f, 0.f, 0.f, 0.f};
  f32x4 acc[4][4];
#pragma unroll
  for (int i = 0; i < 4; i++)
#pragma unroll
    for (int j = 0; j < 4; j++) acc[i][j] = z;

  const int srow = lane >> 3;           // row within 8-row issue group
  const int lc   = (lane & 7) ^ srow;   // logical chunk this lane fetches

  for (int kk = 0; kk < klen; kk += 64) {
    const int k0 = kz0 + kk;
#pragma unroll
    for (int i = 0; i < 4; i++) {
      int rb = w * 32 + i * 8;
      gld_lds16(&A [(size_t)(m0 + rb + srow) * Kfull + k0 + lc * 8], &As[rb * 64]);
      gld_lds16(&Bt[(size_t)(n0 + rb + srow) * Kfull + k0 + lc * 8], &Bs[rb * 64]);
    }
    __syncthreads();
#pragma unroll
    for (int kb = 0; kb < 2; kb++) {
      const int pc = ((kb * 4 + quad) ^ (l16 & 7)) * 8;
      bf16x8 a[4], b[4];
#pragma unroll
      for (int f = 0; f < 4; f++) {
        a[f] = *(const bf16x8*)&As[(wm + f * 16 + l16) * 64 + pc];
        b[f] = *(const bf16x8*)&Bs[(wn + f * 16 + l16) * 64 + pc];
      }
#pragma unroll
      for (int fi = 0; fi < 4; fi++)
#pragma unroll
        for (int fj = 0; fj < 4; fj++)
          acc[fi][fj] = __builtin_amdgcn_mfma_f32_16x16x32_bf16(a[fi], b[fj], acc[fi][fj], 0, 0, 0);
    }
    __syncthreads();
  }

  float* Cz = C + (size_t)blockIdx.z * M * N;
#pragma unroll
  for (int fi = 0; fi < 4; fi++) {
    int row0 = m0 + wm + fi * 16 + quad * 4;
#pragma unroll
    for (int fj = 0; fj < 4; fj++) {
      int col = n0 + wn + fj * 16 + l16;
#pragma unroll
      for (int r = 0; r < 4; r++)
        Cz[(size_t)(row0 + r) * N + col] = acc[fi][fj][r];
    }
  }
}

// ---------------------------------------------------------------- split-K reduce: out = a + b
__global__ __launch_bounds__(256) void add2(const float* __restrict__ a,
                                            const float* __restrict__ b,
                                            float* __restrict__ c, int n4) {
  int i = blockIdx.x * 256 + threadIdx.x;
  if (i >= n4) return;
  f32x4 va = ((const f32x4*)a)[i], vb = ((const f32x4*)b)[i];
  ((f32x4*)c)[i] = va + vb;
}

// ---------------------------------------------------------------- RMSNorm + RoPE; q -> Qb bf16 (pre-scaled), k -> Kb bf16
__global__ __launch_bounds__(64) void rmsnorm_rope_qk(const float* __restrict__ qkv,
                                                      const float* __restrict__ cosT,
                                                      const float* __restrict__ sinT,
                                                      const float* __restrict__ qw,
                                                      const float* __restrict__ kw,
                                                      short* __restrict__ Qb,
                                                      short* __restrict__ Kb) {
  int t    = blockIdx.x;
  int hd   = blockIdx.y;        // 0..35: 0..31 q-heads, 32..35 k-heads
  int b    = t >> 10;
  int s    = t & (S_ - 1);
  int lane = threadIdx.x;
  const float QSC = 0.08838834764831845f * 1.4426950408889634f;  // SCALE*log2(e)
  const float* base;
  const float* w;
  short* dst;
  float osc;
  if (hd < H_) {
    base = qkv + (size_t)t * NQKV + hd * D_;
    w = qw; osc = QSC;
    dst = Qb + (((size_t)b * H_ + hd) * S_ + s) * D_;
  } else {
    base = qkv + (size_t)t * NQKV + H_ * D_ + (hd - H_) * D_;
    w = kw; osc = 1.0f;
    dst = Kb + (((size_t)b * HK_ + (hd - H_)) * S_ + s) * D_;
  }
  float x1 = base[lane], x2 = base[lane + 64];
  float ss = x1 * x1 + x2 * x2;
#pragma unroll
  for (int off = 32; off > 0; off >>= 1) ss += __shfl_xor(ss, off, 64);
  float rn = rsqrtf(ss * (1.0f / 128.0f) + 1e-6f);
  float y1 = x1 * rn * w[lane], y2 = x2 * rn * w[lane + 64];
  float c1 = cosT[s * D_ + lane],      s1 = sinT[s * D_ + lane];
  float c2 = cosT[s * D_ + lane + 64], s2 = sinT[s * D_ + lane + 64];
  dst[lane]      = f2bf((y1 * c1 - y2 * s1) * osc);
  dst[lane + 64] = f2bf((y2 * c2 + y1 * s2) * osc);
}

// ---------------------------------------------------------------- V: fp32 qkv slice -> bf16 transposed [b][kh][D][S]
__global__ __launch_bounds__(256) void v_pack(const float* __restrict__ qkv,
                                              short* __restrict__ Vt) {
  int bk = blockIdx.x;            // 0..7 = b*HK+kh
  int s0 = blockIdx.y * 64;
  int d  = threadIdx.x & 127;
  int sg = threadIdx.x >> 7;
  int b = bk >> 2, kh = bk & 3;
  short buf[32];
  const float* src = qkv + ((size_t)(b * S_ + s0 + sg * 32)) * NQKV + (H_ + HK_) * D_ + kh * D_ + d;
#pragma unroll
  for (int sj = 0; sj < 32; sj++)
    buf[sj] = f2bf(src[(size_t)sj * NQKV]);
  short* dst = Vt + ((size_t)bk * D_ + d) * S_ + s0 + sg * 32;
#pragma unroll
  for (int i = 0; i < 4; i++) ((i32x4*)dst)[i] = ((const i32x4*)buf)[i];
}

// ---------------------------------------------------------------- MFMA flash attention v2
// Q-tile 128/block (wave owns 32 rows via fi=0,1), K/V-tile 64. K/V staged with
// global_load_lds(16) into XOR-swizzled [row][64] (m97-proven). l accumulated via
// ones-rows in Vs (PV nb2=8 column) — no sum shuffles.
__global__ __launch_bounds__(256) void attn_mfma2(const short* __restrict__ Qb,
                                                  const short* __restrict__ Kb,
                                                  const short* __restrict__ Vt,
                                                  short* __restrict__ ctx) {
  const int qt = (int)gridDim.x - 1 - blockIdx.x;   // biggest tiles first
  const int h  = blockIdx.y;
  const int b  = blockIdx.z;
  const int kh = h >> 3;          // G = 8
  const int q0 = qt * 128;
  const int tid = threadIdx.x, w = tid >> 6, lane = tid & 63;
  const int quad = lane >> 4, l16 = lane & 15;

  __shared__ short Ks[128 * 64];        // K tile: row' = key*2 + dhalf, XOR-swizzled
  __shared__ short Vs[144 * 64];        // V^T tile: row = d (128..143 = ones), XOR-swizzled
  __shared__ short Ps[4][2][16 * 72];   // per-(wave,fi) P [qrow][key]

  // ones rows for the l-column trick
  for (int i = tid; i < 16 * 64; i += 256) Vs[128 * 64 + i] = (short)0x3F80;

  // ---- Q A-frags straight from global: rows fi*64 + w*16 + l16
  const short* Qbase = Qb + (((size_t)b * H_ + h) * S_ + q0) * D_;
  bf16x8 aq[2][4];
#pragma unroll
  for (int fi = 0; fi < 2; fi++)
#pragma unroll
    for (int kb = 0; kb < 4; kb++)
      aq[fi][kb] = *(const bf16x8*)&Qbase[(size_t)(fi * 64 + w * 16 + l16) * D_ + kb * 32 + quad * 8];

  const f32x4 z = {0.f, 0.f, 0.f, 0.f};
  f32x4 O[2][9];                        // nb2=8 is the l column
#pragma unroll
  for (int fi = 0; fi < 2; fi++)
#pragma unroll
    for (int n = 0; n < 9; n++) O[fi][n] = z;
  float m_r[2][4] = {{-1e30f, -1e30f, -1e30f, -1e30f}, {-1e30f, -1e30f, -1e30f, -1e30f}};

  const short* Kbase = Kb + ((size_t)(b * HK_ + kh) * S_) * D_;
  const short* Vbase = Vt + ((size_t)(b * HK_ + kh) * D_) * S_;

  const int srow = lane >> 3;
  const int lc   = (lane & 7) ^ srow;

  const int nkt = 2 * qt + 2;
  for (int kt = 0; kt < nkt; kt++) {
    const int k0 = kt * 64;
    __syncthreads();   // previous iter's readers done (also orders ones-init/Q-loads)
#pragma unroll
    for (int i = 0; i < 4; i++) {
      int rb = w * 32 + i * 8;
      int rr = rb + srow;                          // K row' = key*2 + half
      gld_lds16(&Kbase[(size_t)(k0 + (rr >> 1)) * D_ + (rr & 1) * 64 + lc * 8], &Ks[rb * 64]);
      gld_lds16(&Vbase[(size_t)rr * S_ + k0 + lc * 8], &Vs[rb * 64]);   // V row = d
    }
    __syncthreads();   // drains vmcnt (compiler emits waitcnt before barrier)

#pragma unroll
    for (int fi = 0; fi < 2; fi++) {
      if (kt > 2 * qt + fi) continue;   // fi=0 fully masked at the last tile

      // ---- QK^T
      f32x4 Sc[4] = {z, z, z, z};
#pragma unroll
      for (int kb = 0; kb < 4; kb++) {
        const int h2 = kb >> 1;                     // d-half of chunk kb*4+quad
        const int c7 = (kb & 1) * 4 + quad;         // chunk&7
#pragma unroll
        for (int nb = 0; nb < 4; nb++) {
          int rr = 2 * (nb * 16 + l16) + h2;
          bf16x8 bk = *(const bf16x8*)&Ks[rr * 64 + (c7 ^ (rr & 7)) * 8];
          Sc[nb] = __builtin_amdgcn_mfma_f32_16x16x32_bf16(aq[fi][kb], bk, Sc[nb], 0, 0, 0);
        }
      }
      if (kt == 2 * qt + fi) {   // diagonal tile mask
#pragma unroll
        for (int nb = 0; nb < 4; nb++) {
          int col = k0 + nb * 16 + l16;
#pragma unroll
          for (int r = 0; r < 4; r++) {
            int row = q0 + fi * 64 + w * 16 + quad * 4 + r;
            if (col > row) Sc[nb][r] = -1e30f;
          }
        }
      }

      // ---- online softmax: max-reduce over l16 lanes only (sum via MFMA ones-column)
      float alpha[4];
#pragma unroll
      for (int r = 0; r < 4; r++) {
        float mx = fmaxf(fmaxf(Sc[0][r], Sc[1][r]), fmaxf(Sc[2][r], Sc[3][r]));
#pragma unroll
        for (int off = 1; off < 16; off <<= 1) mx = fmaxf(mx, __shfl_xor(mx, off, 64));
        float mn = fmaxf(m_r[fi][r], mx);
        alpha[r] = exp2f(m_r[fi][r] - mn);
        m_r[fi][r] = mn;
#pragma unroll
        for (int nb = 0; nb < 4; nb++) Sc[nb][r] = exp2f(Sc[nb][r] - mn);
      }

      // ---- P (C-layout) -> per-(wave,fi) LDS region
#pragma unroll
      for (int nb = 0; nb < 4; nb++)
#pragma unroll
        for (int r = 0; r < 4; r++)
          Ps[w][fi][(quad * 4 + r) * 72 + nb * 16 + l16] = f2bf(Sc[nb][r]);

      // ---- rescale O (incl. l column)
#pragma unroll
      for (int n = 0; n < 9; n++)
#pragma unroll
        for (int r = 0; r < 4; r++) O[fi][n][r] *= alpha[r];

      // ---- PV: A = P [qrow][key], B = V^T rows d (swizzled); nb2=8 = ones -> l
#pragma unroll
      for (int kb2 = 0; kb2 < 2; kb2++) {
        bf16x8 ap = *(const bf16x8*)&Ps[w][fi][l16 * 72 + kb2 * 32 + quad * 8];
        const int c7 = kb2 * 4 + quad;              // key-chunk 0..7
#pragma unroll
        for (int nb2 = 0; nb2 < 9; nb2++) {
          int d = nb2 * 16 + l16;
          bf16x8 bv = *(const bf16x8*)&Vs[d * 64 + (c7 ^ (d & 7)) * 8];
          O[fi][nb2] = __builtin_amdgcn_mfma_f32_16x16x32_bf16(ap, bv, O[fi][nb2], 0, 0, 0);
        }
      }
    }
  }

  // ---- epilogue: every lane's O[fi][8][r] == l (all ones-rows identical)
#pragma unroll
  for (int fi = 0; fi < 2; fi++)
#pragma unroll
    for (int r = 0; r < 4; r++) {
      float inv = 1.0f / O[fi][8][r];
      size_t row = (size_t)(b * S_ + q0 + fi * 64 + w * 16 + quad * 4 + r);
      short* dst = ctx + row * (H_ * D_) + h * D_;
#pragma unroll
      for (int nb2 = 0; nb2 < 8; nb2++)
        dst[nb2 * 16 + l16] = f2bf(O[fi][nb2][r] * inv);
    }
}

// ---------------------------------------------------------------- launch
extern "C" void kernel_launch(void* const* d_in, const int* in_sizes, int n_in,
                              void* d_out, int out_size, void* d_ws, size_t ws_size,
                              hipStream_t stream) {
  (void)in_sizes; (void)n_in; (void)out_size; (void)ws_size;
  const float* hidden = (const float*)d_in[0];
  const float* cosT   = (const float*)d_in[1];
  const float* sinT   = (const float*)d_in[2];
  const float* wqkv   = (const float*)d_in[3];
  const float* qnw    = (const float*)d_in[4];
  const float* knw    = (const float*)d_in[5];
  const float* wo     = (const float*)d_in[6];
  float* out = (float*)d_out;

  char* ws = (char*)d_ws;
  float* qkv = (float*)(ws);                                  // 40 MB (dead after rmsnorm+v_pack)
  short* hb  = (short*)(ws + 41943040);                       // 8 MB: hidden bf16 (dead after gemm1)
  short* wT  = (short*)(ws + 41943040 + 8388608);             // 20 MB: w^T (gemm1), then Qb, then w_o^T
  short* ctx = (short*)(ws + 41943040 + 8388608 + 20971520);  // 16 MB: ctx bf16
  short* Kb  = hb;                                            // 2 MB (after gemm1)
  short* Vt  = hb + 1048576;                                  // 2 MB
  short* Qb  = wT;                                            // 16 MB (after gemm1)
  float* part = (float*)ws;                                   // 32 MB split-K partials (qkv dead by then)

  // 1. hidden -> bf16
  cast_f32_bf16<<<4096, 256, 0, stream>>>(hidden, hb, TOK * HID_ / 4);
  // 2. w_qkv [2048][5120] -> bf16 [5120][2048]
  transpose_cast<<<dim3(NQKV / 32, HID_ / 32), 256, 0, stream>>>(wqkv, wT, HID_, NQKV);
  // 3. qkv = hidden @ w_qkv   (M=2048, N=5120, K=2048)
  gemm_bt128<<<dim3(NQKV / 128, TOK / 128, 1), 256, 0, stream>>>(hb, wT, qkv, TOK, NQKV, HID_, HID_);
  // 4. RMSNorm + RoPE -> Qb (pre-scaled bf16), Kb (bf16)
  rmsnorm_rope_qk<<<dim3(TOK, H_ + HK_), 64, 0, stream>>>(qkv, cosT, sinT, qnw, knw, Qb, Kb);
  // 5. V slice -> bf16 transposed [b][kh][D][S]
  v_pack<<<dim3(B_ * HK_, S_ / 64), 256, 0, stream>>>(qkv, Vt);
  // 6. MFMA causal GQA flash attention -> ctx bf16 [2048][4096]
  attn_mfma2<<<dim3(S_ / 128, H_, B_), 256, 0, stream>>>(Qb, Kb, Vt, ctx);
  // 7. w_o [4096][2048] -> bf16 [2048][4096]   [clobbers Qb — attention done]
  transpose_cast<<<dim3(HID_ / 32, (H_ * D_) / 32), 256, 0, stream>>>(wo, wT, H_ * D_, HID_);
  // 8. out = ctx @ w_o, split-K=2 (512 blocks -> 2/CU co-resident), then reduce
  gemm_bt128<<<dim3(HID_ / 128, TOK / 128, 2), 256, 0, stream>>>(ctx, wT, part, TOK, HID_, H_ * D_, (H_ * D_) / 2);
  add2<<<(TOK * HID_ / 4 + 255) / 256, 256, 0, stream>>>(part, part + (size_t)TOK * HID_, out, TOK * HID_ / 4);
}